// Round 7
// baseline (389.669 us; speedup 1.0000x reference)
//
#include <hip/hip_runtime.h>
#include <math.h>

#define Bn 4
#define Ln 1024
#define Sn 1024
#define Hn 8
#define En 64

typedef __attribute__((ext_vector_type(4))) float f32x4;
typedef __attribute__((ext_vector_type(8))) _Float16 h16x8;
typedef __attribute__((ext_vector_type(4))) _Float16 h16x4;

__device__ __forceinline__ float frcp(float x) { return __builtin_amdgcn_rcpf(x); }
__device__ __forceinline__ float fexp2(float x) {
    float r; asm("v_exp_f32 %0, %1" : "=v"(r) : "v"(x)); return r;
}
__device__ __forceinline__ float flog2(float x) {
    float r; asm("v_log_f32 %0, %1" : "=v"(r) : "v"(x)); return r;
}

// ---------------------------------------------------------------------------
// prep: split Q,K fp32 -> f16 hi/lo, fragment-major layout
//   [bh][tile][kq][row][8]; V -> f16 transposed tiles, same layout.
// Re-gridded to 2048 blocks (16-row slabs, 8 blocks/CU) — round-6 finding:
// the old 512-block version was part of a stable ~200us non-fused gap.
// Also folds Vout/ent zero-init (replaces 2 hipMemsetAsync graph nodes).
// ---------------------------------------------------------------------------
__global__ __launch_bounds__(256) void prep(
    const float* __restrict__ Q, const float* __restrict__ K,
    const float* __restrict__ V,
    _Float16* __restrict__ Qh, _Float16* __restrict__ Ql,
    _Float16* __restrict__ Kh, _Float16* __restrict__ Kl,
    _Float16* __restrict__ Vt, float* __restrict__ Vout,
    float* __restrict__ entOut) {
    __shared__ float vlds[16][69];
    const int bx = blockIdx.x;   // 0..63: st = bx>>2, row-group = bx&3
    const int st = bx >> 2;
    const int rg = bx & 3;
    const int bh = blockIdx.y;   // 0..31
    const int b = bh >> 3, h = bh & 7;
    const int tid = threadIdx.x;
    const int s0 = st * 64;

    // ---- zero-init Vout (4 f32/thread) and ent ----
    {
        const int flat = (blockIdx.y * 64 + bx) * 256 + tid;   // 0..524287
        *(f32x4*)(Vout + (size_t)flat * 4) = (f32x4){0.f, 0.f, 0.f, 0.f};
        if (flat < 8192) *(f32x4*)(entOut + (size_t)flat * 4) = (f32x4){0.f, 0.f, 0.f, 0.f};
    }

    // ---- load 16 rows, convert, store fragment-major; V slab to LDS ----
    {
        const int r16 = tid >> 4;            // 0..15
        const int c4 = (tid & 15) << 2;      // 0,4..60
        const int row = rg * 16 + r16;       // 0..63 in tile
        size_t gin = (((size_t)b * Ln + s0 + row) * Hn + h) * En + c4;
        f32x4 qv = *(const f32x4*)(Q + gin);
        f32x4 kv = *(const f32x4*)(K + gin);
        f32x4 vv = *(const f32x4*)(V + gin);
        vlds[r16][c4 + 0] = vv.x; vlds[r16][c4 + 1] = vv.y;
        vlds[r16][c4 + 2] = vv.z; vlds[r16][c4 + 3] = vv.w;
        h16x4 qh4, ql4, kh4, kl4;
#pragma unroll
        for (int j = 0; j < 4; ++j) {
            float x = qv[j];
            _Float16 hx = (_Float16)x;
            qh4[j] = hx; ql4[j] = (_Float16)(x - (float)hx);
            float y = kv[j];
            _Float16 hy = (_Float16)y;
            kh4[j] = hy; kl4[j] = (_Float16)(y - (float)hy);
        }
        size_t ob = ((((size_t)bh * 16 + st) * 8 + (c4 >> 3)) * 64 + row) * 8 + (c4 & 7);
        *(h16x4*)(Qh + ob) = qh4; *(h16x4*)(Ql + ob) = ql4;
        *(h16x4*)(Kh + ob) = kh4; *(h16x4*)(Kl + ob) = kl4;
    }
    __syncthreads();
    // ---- transposed V slab: 64 d-rows x 16 s-cols ----
    {
        const int d = tid >> 2;              // 0..63
        const int sgl = (tid & 3) << 2;      // 0,4,8,12
        h16x4 v4;
#pragma unroll
        for (int j = 0; j < 4; ++j) v4[j] = (_Float16)vlds[sgl + j][d];
        const int sg = rg * 16 + sgl;
        size_t ob = ((((size_t)bh * 16 + st) * 8 + (sg >> 3)) * 64 + d) * 8 + (sg & 7);
        *(h16x4*)(Vt + ob) = v4;
    }
}

// ---------------------------------------------------------------------------
// prep2: batch-independent mask precompute.
//   mh[h][l][s] = 0.125 * sigmoid((log(u+eps)-log(1-u+eps)+phi)/tau) * hard
// ---------------------------------------------------------------------------
__global__ __launch_bounds__(256) void prep2(
    const float* __restrict__ phi, const float* __restrict__ u,
    const float* __restrict__ hard, const float* __restrict__ p_lt,
    _Float16* __restrict__ mh) {
    const float tau = fminf(fmaxf(expf(p_lt[0]), 0.1f), 5.0f);
    const float itau = 1.0f / tau;
    const size_t base = ((size_t)blockIdx.x * 256 + threadIdx.x) * 8;
    const size_t ls = base & (size_t)(Ln * Sn - 1);
    f32x4 ph0 = *(const f32x4*)(phi + base);
    f32x4 ph1 = *(const f32x4*)(phi + base + 4);
    f32x4 uu0 = *(const f32x4*)(u + base);
    f32x4 uu1 = *(const f32x4*)(u + base + 4);
    f32x4 hm0 = *(const f32x4*)(hard + ls);
    f32x4 hm1 = *(const f32x4*)(hard + ls + 4);
    h16x8 o;
#pragma unroll
    for (int j = 0; j < 4; ++j) {
        float z = (__logf((uu0[j] + 1e-8f) * frcp(1.0f - uu0[j] + 1e-8f)) + ph0[j]) * itau;
        float m = frcp(1.0f + __expf(-z));
        o[j] = (_Float16)(0.125f * m * hm0[j]);
    }
#pragma unroll
    for (int j = 0; j < 4; ++j) {
        float z = (__logf((uu1[j] + 1e-8f) * frcp(1.0f - uu1[j] + 1e-8f)) + ph1[j]) * itau;
        float m = frcp(1.0f + __expf(-z));
        o[4 + j] = (_Float16)(0.125f * m * hm1[j]);
    }
    *(h16x8*)(mh + base) = o;
}

// ---------------------------------------------------------------------------
// fused: barrier-free, XCD-pinned, NT A-stores, per-sub QK/EW fusion.
// Grid = flat 2048 (s-quarters); bijective swizzle work = (f&7)*256+(f>>3)
// pins head h = XCD. Per-sub fusion cuts QK accumulator live range from
// 32 to 8 VGPRs (round-6 finding: occupancy was register-capped at
// 4 waves/SIMD, VGPR64+acc~64=128/wave; target ~96 -> 5 waves/SIMD).
// NT stores keep the 128MB A stream out of L2 (round 6: FETCH 132->65 MB).
// launch_bounds(256,4): do NOT clamp harder — (256,8) spilled 3x (round 4).
// ---------------------------------------------------------------------------
__global__ __launch_bounds__(256, 4) void fused_lie(
    const _Float16* __restrict__ Qh, const _Float16* __restrict__ Ql,
    const _Float16* __restrict__ Kh, const _Float16* __restrict__ Kl,
    const _Float16* __restrict__ Vt, const _Float16* __restrict__ mh,
    const float* __restrict__ p_lg, const float* __restrict__ p_ltc,
    float* __restrict__ Aout, float* __restrict__ Vout,
    float* __restrict__ entOut) {
    __shared__ __align__(16) _Float16 plds[4][16 * 72];

    // ---- XCD-pinned work decode (8 XCDs, flat%8 = XCD assumption) ----
    const int f = blockIdx.x;                 // 0..2047
    const int work = (f & 7) * 256 + (f >> 3);
    const int h = work >> 8;                  // 0..7  == XCD
    const int rem = work & 255;
    const int b = rem >> 6;                   // 0..3
    const int tile = rem & 63;
    const int lt = tile >> 2;                 // 0..15
    const int sq = tile & 3;                  // s-quarter 0..3
    const int bh = b * Hn + h;
    const int tid = threadIdx.x;
    const int w = tid >> 6;
    const int lane = tid & 63;
    const int q = lane >> 4;
    const int n = lane & 15;
    const int l0 = lt * 64;

    const float gain = fminf(fmaxf(expf(p_lg[0]), 1e-3f), 1000.0f);
    const float tauc = fminf(fmaxf(expf(p_ltc[0]), 1e-3f), 10.0f);
    const float c2l = 2.0f * gain / tauc * 1.44269504f;   // exp(c2*x) = exp2(c2l*x)

    // A-side fragments (registers): rows l0+w*16+n, k-chunk q+4*kh
    h16x8 QAh[2], QAl[2], KAh[2], KAl[2];
    {
        const size_t ab = (((size_t)bh * 16 + lt) * 8) * 512 + (size_t)(w * 16 + n) * 8;
#pragma unroll
        for (int kh = 0; kh < 2; ++kh) {
            size_t off = ab + (size_t)(q + 4 * kh) * 512;
            QAh[kh] = *(const h16x8*)(Qh + off);
            QAl[kh] = *(const h16x8*)(Ql + off);
            KAh[kh] = *(const h16x8*)(Kh + off);
            KAl[kh] = *(const h16x8*)(Kl + off);
        }
    }

    f32x4 accV[4];
#pragma unroll
    for (int i = 0; i < 4; ++i) accV[i] = (f32x4){0.f, 0.f, 0.f, 0.f};
    float entp[4] = {0.f, 0.f, 0.f, 0.f};

    const int lbase = l0 + w * 16 + q * 4;
    float* __restrict__ arow = Aout + (((size_t)b * Hn + h) * Ln + lbase) * (size_t)Sn;
    const _Float16* __restrict__ ment = mh + ((size_t)h * Ln + lbase) * (size_t)Sn;

    for (int stc = 0; stc < 4; ++stc) {
        const int st = sq * 4 + stc;
        const int s0 = st * 64;
        const size_t tb = (((size_t)bh * 16 + st) * 8) * 512;

        // ---- per-sub: 12 MFMA (f16 split, both orientations) -> EW chain ----
#pragma unroll
        for (int sub = 0; sub < 4; ++sub) {
            f32x4 x1 = (f32x4){0.f, 0.f, 0.f, 0.f};
            f32x4 x2 = (f32x4){0.f, 0.f, 0.f, 0.f};
#pragma unroll
            for (int kh = 0; kh < 2; ++kh) {
                const size_t off = tb + (size_t)(q + 4 * kh) * 512 + (size_t)(sub * 16 + n) * 8;
                h16x8 KBh = *(const h16x8*)(Kh + off);
                h16x8 KBl = *(const h16x8*)(Kl + off);
                h16x8 QBh = *(const h16x8*)(Qh + off);
                h16x8 QBl = *(const h16x8*)(Ql + off);
                x1 = __builtin_amdgcn_mfma_f32_16x16x32_f16(QAh[kh], KBh, x1, 0, 0, 0);
                x1 = __builtin_amdgcn_mfma_f32_16x16x32_f16(QAh[kh], KBl, x1, 0, 0, 0);
                x1 = __builtin_amdgcn_mfma_f32_16x16x32_f16(QAl[kh], KBh, x1, 0, 0, 0);
                x2 = __builtin_amdgcn_mfma_f32_16x16x32_f16(KAh[kh], QBh, x2, 0, 0, 0);
                x2 = __builtin_amdgcn_mfma_f32_16x16x32_f16(KAh[kh], QBl, x2, 0, 0, 0);
                x2 = __builtin_amdgcn_mfma_f32_16x16x32_f16(KAl[kh], QBh, x2, 0, 0, 0);
            }
            // ---- elementwise (C-layout: row q*4+r, col sub*16+n) ----
            const int s = s0 + sub * 16 + n;
#pragma unroll
            for (int r = 0; r < 4; ++r) {
                float mhv = (float)ment[(size_t)r * Sn + s];
                float cm = x1[r] - x2[r];
                // tanh(c1*cm) = 1 - 2/(exp2(c2l*cm)+1)
                float x = 1.0f - 2.0f * frcp(fexp2(c2l * cm) + 1.0f);
                // tanh-form gelu: x * sigmoid(1.5957691*(x + 0.044715 x^3))
                float t = x * fmaf(0.044715f * x, x, 1.0f);
                float g = x * frcp(1.0f + fexp2(-2.30221271f * t));
                float att = g * mhv;               // mh carries 0.125*m*hard
                __builtin_nontemporal_store(att, &arow[(size_t)r * Sn + s]);
                entp[r] += att * flog2(fmaxf(att, 1e-8f));
                plds[w][(q * 4 + r) * 72 + sub * 16 + n] = (_Float16)att;
            }
        }
        asm volatile("" ::: "memory");   // order plds writes before PV reads

        // ---- PV: accV += P . V (P A-frags from per-warp LDS, V^T global) ----
        {
            const _Float16* pw = &plds[w][0];
#pragma unroll
            for (int kh = 0; kh < 2; ++kh) {
                const size_t kqb = tb + (size_t)(q + 4 * kh) * 512;
                h16x8 Pf = *(const h16x8*)&pw[n * 72 + q * 8 + kh * 32];
#pragma unroll
                for (int sub = 0; sub < 4; ++sub) {
                    h16x8 Vf = *(const h16x8*)(Vt + kqb + (size_t)(sub * 16 + n) * 8);
                    accV[sub] = __builtin_amdgcn_mfma_f32_16x16x32_f16(Pf, Vf, accV[sub], 0, 0, 0);
                }
            }
        }
        asm volatile("" ::: "memory");   // order PV reads before next chunk's writes
    }

    // ---- epilogue: V partial sums via atomics (4 s-quarter blocks per l) ----
#pragma unroll
    for (int sub = 0; sub < 4; ++sub) {
#pragma unroll
        for (int r = 0; r < 4; ++r) {
            const int l = l0 + w * 16 + q * 4 + r;
            atomicAdd(Vout + (((size_t)b * Ln + l) * Hn + h) * En + sub * 16 + n, accV[sub][r]);
        }
    }
    // ---- entropy: quad-row reduce over 16 lanes, atomic partial (ln2 scale) ----
#pragma unroll
    for (int r = 0; r < 4; ++r) {
        float v = entp[r];
        v += __shfl_xor(v, 1);
        v += __shfl_xor(v, 2);
        v += __shfl_xor(v, 4);
        v += __shfl_xor(v, 8);
        if (n == 0) {
            atomicAdd(entOut + ((size_t)b * Hn + h) * Ln + lbase + r, -v * 0.69314718f);
        }
    }
}

extern "C" void kernel_launch(void* const* d_in, const int* in_sizes, int n_in,
                              void* d_out, int out_size, void* d_ws, size_t ws_size,
                              hipStream_t stream) {
    (void)in_sizes; (void)n_in; (void)ws_size; (void)out_size;

    const float* Q    = (const float*)d_in[0];   // (B,L,H,E)
    const float* K    = (const float*)d_in[1];   // (B,S,H,E)
    const float* Vv   = (const float*)d_in[2];   // (B,S,H,E)
    const float* phi  = (const float*)d_in[3];   // (H,L,S)
    const float* lg   = (const float*)d_in[4];
    const float* ltau = (const float*)d_in[5];
    const float* ltc  = (const float*)d_in[6];
    const float* hard = (const float*)d_in[7];   // (L,S)
    const float* u    = (const float*)d_in[8];   // (H,L,S)

    float* out  = (float*)d_out;
    float* Vout = out;                                 // B*L*H*E
    float* Aout = out + (size_t)Bn * Ln * Hn * En;     // B*H*L*S
    float* ent  = Aout + (size_t)Bn * Hn * Ln * Sn;    // B*H*L

    const size_t NE = (size_t)32 * 1024 * 64;          // 2.1M halves per array
    _Float16* Qh = (_Float16*)d_ws;
    _Float16* Ql = Qh + NE;
    _Float16* Kh = Ql + NE;
    _Float16* Kl = Kh + NE;
    _Float16* Vt = Kl + NE;
    _Float16* mh = Vt + NE;                            // H*L*S halves (16 MB)

    prep<<<dim3(64, 32), 256, 0, stream>>>(Q, K, Vv, Qh, Ql, Kh, Kl, Vt, Vout, ent);
    prep2<<<dim3(4096), 256, 0, stream>>>(phi, u, hard, ltau, mh);
    fused_lie<<<dim3(2048), 256, 0, stream>>>(Qh, Ql, Kh, Kl, Vt, mh,
                                              lg, ltc, Aout, Vout, ent);
}

// Round 8
// 373.228 us; speedup vs baseline: 1.0441x; 1.0441x over previous
//
#include <hip/hip_runtime.h>
#include <math.h>

#define Bn 4
#define Ln 1024
#define Sn 1024
#define Hn 8
#define En 64

typedef __attribute__((ext_vector_type(4))) float f32x4;
typedef __attribute__((ext_vector_type(8))) _Float16 h16x8;
typedef __attribute__((ext_vector_type(4))) _Float16 h16x4;

__device__ __forceinline__ float frcp(float x) { return __builtin_amdgcn_rcpf(x); }
__device__ __forceinline__ float fexp2(float x) {
    float r; asm("v_exp_f32 %0, %1" : "=v"(r) : "v"(x)); return r;
}
__device__ __forceinline__ float flog2(float x) {
    float r; asm("v_log_f32 %0, %1" : "=v"(r) : "v"(x)); return r;
}

// ---------------------------------------------------------------------------
// prep: split Q,K fp32 -> f16 hi/lo, fragment-major layout
//   [bh][tile][kq][row][8]; V -> f16 transposed tiles, same layout.
// 2048 blocks; folds Vout/ent zero-init (replaces 2 hipMemsetAsync nodes).
// ---------------------------------------------------------------------------
__global__ __launch_bounds__(256) void prep(
    const float* __restrict__ Q, const float* __restrict__ K,
    const float* __restrict__ V,
    _Float16* __restrict__ Qh, _Float16* __restrict__ Ql,
    _Float16* __restrict__ Kh, _Float16* __restrict__ Kl,
    _Float16* __restrict__ Vt, float* __restrict__ Vout,
    float* __restrict__ entOut) {
    __shared__ float vlds[16][69];
    const int bx = blockIdx.x;   // 0..63: st = bx>>2, row-group = bx&3
    const int st = bx >> 2;
    const int rg = bx & 3;
    const int bh = blockIdx.y;   // 0..31
    const int b = bh >> 3, h = bh & 7;
    const int tid = threadIdx.x;
    const int s0 = st * 64;

    // ---- zero-init Vout (4 f32/thread) and ent ----
    {
        const int flat = (blockIdx.y * 64 + bx) * 256 + tid;   // 0..524287
        *(f32x4*)(Vout + (size_t)flat * 4) = (f32x4){0.f, 0.f, 0.f, 0.f};
        if (flat < 8192) *(f32x4*)(entOut + (size_t)flat * 4) = (f32x4){0.f, 0.f, 0.f, 0.f};
    }

    // ---- load 16 rows, convert, store fragment-major; V slab to LDS ----
    {
        const int r16 = tid >> 4;            // 0..15
        const int c4 = (tid & 15) << 2;      // 0,4..60
        const int row = rg * 16 + r16;       // 0..63 in tile
        size_t gin = (((size_t)b * Ln + s0 + row) * Hn + h) * En + c4;
        f32x4 qv = *(const f32x4*)(Q + gin);
        f32x4 kv = *(const f32x4*)(K + gin);
        f32x4 vv = *(const f32x4*)(V + gin);
        vlds[r16][c4 + 0] = vv.x; vlds[r16][c4 + 1] = vv.y;
        vlds[r16][c4 + 2] = vv.z; vlds[r16][c4 + 3] = vv.w;
        h16x4 qh4, ql4, kh4, kl4;
#pragma unroll
        for (int j = 0; j < 4; ++j) {
            float x = qv[j];
            _Float16 hx = (_Float16)x;
            qh4[j] = hx; ql4[j] = (_Float16)(x - (float)hx);
            float y = kv[j];
            _Float16 hy = (_Float16)y;
            kh4[j] = hy; kl4[j] = (_Float16)(y - (float)hy);
        }
        size_t ob = ((((size_t)bh * 16 + st) * 8 + (c4 >> 3)) * 64 + row) * 8 + (c4 & 7);
        *(h16x4*)(Qh + ob) = qh4; *(h16x4*)(Ql + ob) = ql4;
        *(h16x4*)(Kh + ob) = kh4; *(h16x4*)(Kl + ob) = kl4;
    }
    __syncthreads();
    // ---- transposed V slab: 64 d-rows x 16 s-cols ----
    {
        const int d = tid >> 2;              // 0..63
        const int sgl = (tid & 3) << 2;      // 0,4,8,12
        h16x4 v4;
#pragma unroll
        for (int j = 0; j < 4; ++j) v4[j] = (_Float16)vlds[sgl + j][d];
        const int sg = rg * 16 + sgl;
        size_t ob = ((((size_t)bh * 16 + st) * 8 + (sg >> 3)) * 64 + d) * 8 + (sg & 7);
        *(h16x4*)(Vt + ob) = v4;
    }
}

// ---------------------------------------------------------------------------
// prep2: batch-independent mask precompute.
//   mh[h][l][s] = 0.125 * sigmoid((log(u+eps)-log(1-u+eps)+phi)/tau) * hard
// ---------------------------------------------------------------------------
__global__ __launch_bounds__(256) void prep2(
    const float* __restrict__ phi, const float* __restrict__ u,
    const float* __restrict__ hard, const float* __restrict__ p_lt,
    _Float16* __restrict__ mh) {
    const float tau = fminf(fmaxf(expf(p_lt[0]), 0.1f), 5.0f);
    const float itau = 1.0f / tau;
    const size_t base = ((size_t)blockIdx.x * 256 + threadIdx.x) * 8;
    const size_t ls = base & (size_t)(Ln * Sn - 1);
    f32x4 ph0 = *(const f32x4*)(phi + base);
    f32x4 ph1 = *(const f32x4*)(phi + base + 4);
    f32x4 uu0 = *(const f32x4*)(u + base);
    f32x4 uu1 = *(const f32x4*)(u + base + 4);
    f32x4 hm0 = *(const f32x4*)(hard + ls);
    f32x4 hm1 = *(const f32x4*)(hard + ls + 4);
    h16x8 o;
#pragma unroll
    for (int j = 0; j < 4; ++j) {
        float z = (__logf((uu0[j] + 1e-8f) * frcp(1.0f - uu0[j] + 1e-8f)) + ph0[j]) * itau;
        float m = frcp(1.0f + __expf(-z));
        o[j] = (_Float16)(0.125f * m * hm0[j]);
    }
#pragma unroll
    for (int j = 0; j < 4; ++j) {
        float z = (__logf((uu1[j] + 1e-8f) * frcp(1.0f - uu1[j] + 1e-8f)) + ph1[j]) * itau;
        float m = frcp(1.0f + __expf(-z));
        o[4 + j] = (_Float16)(0.125f * m * hm1[j]);
    }
    *(h16x8*)(mh + base) = o;
}

// ---------------------------------------------------------------------------
// fused: barrier-free, XCD-pinned, NT A-stores. Round-6 structure restored:
// grid 1024 (s-halves), GROUPED EW loop (adjacent 64B NT stores stay
// temporally adjacent -> write-combine into full lines; round 7's per-sub
// split un-merged them: FETCH 65->273 MB, WRITE 203->309 MB. Never separate
// adjacent NT half-line stores).
// New this round: (a) no asm memory fences (intra-wave plds deps are
// compiler-ordered; fences blocked cross-chunk load hoisting);
// (b) V-fragments prefetched into regs at chunk start (+32 VGPR, free:
// occupancy is grid-capped at 4 blocks/CU, VGPR budget 128).
// launch_bounds(256,4): (256,8) spilled 3x (round 4).
// ---------------------------------------------------------------------------
__global__ __launch_bounds__(256, 4) void fused_lie(
    const _Float16* __restrict__ Qh, const _Float16* __restrict__ Ql,
    const _Float16* __restrict__ Kh, const _Float16* __restrict__ Kl,
    const _Float16* __restrict__ Vt, const _Float16* __restrict__ mh,
    const float* __restrict__ p_lg, const float* __restrict__ p_ltc,
    float* __restrict__ Aout, float* __restrict__ Vout,
    float* __restrict__ entOut) {
    __shared__ __align__(16) _Float16 plds[4][16 * 72];

    // ---- XCD-pinned work decode (8 XCDs, flat%8 = XCD assumption) ----
    const int f = blockIdx.x;                 // 0..1023
    const int work = (f & 7) * 128 + (f >> 3);
    const int h = work >> 7;                  // 0..7  == XCD
    const int rem = work & 127;
    const int b = rem >> 5;                   // 0..3
    const int tile = rem & 31;
    const int lt = tile >> 1;                 // 0..15
    const int sh = tile & 1;                  // s-half 0..1
    const int bh = b * Hn + h;
    const int tid = threadIdx.x;
    const int w = tid >> 6;
    const int lane = tid & 63;
    const int q = lane >> 4;
    const int n = lane & 15;
    const int l0 = lt * 64;

    const float gain = fminf(fmaxf(expf(p_lg[0]), 1e-3f), 1000.0f);
    const float tauc = fminf(fmaxf(expf(p_ltc[0]), 1e-3f), 10.0f);
    const float c2l = 2.0f * gain / tauc * 1.44269504f;   // exp(c2*x) = exp2(c2l*x)

    // A-side fragments (registers): rows l0+w*16+n, k-chunk q+4*kh
    h16x8 QAh[2], QAl[2], KAh[2], KAl[2];
    {
        const size_t ab = (((size_t)bh * 16 + lt) * 8) * 512 + (size_t)(w * 16 + n) * 8;
#pragma unroll
        for (int kh = 0; kh < 2; ++kh) {
            size_t off = ab + (size_t)(q + 4 * kh) * 512;
            QAh[kh] = *(const h16x8*)(Qh + off);
            QAl[kh] = *(const h16x8*)(Ql + off);
            KAh[kh] = *(const h16x8*)(Kh + off);
            KAl[kh] = *(const h16x8*)(Kl + off);
        }
    }

    f32x4 accV[4];
#pragma unroll
    for (int i = 0; i < 4; ++i) accV[i] = (f32x4){0.f, 0.f, 0.f, 0.f};
    float entp[4] = {0.f, 0.f, 0.f, 0.f};

    const int lbase = l0 + w * 16 + q * 4;
    float* __restrict__ arow = Aout + (((size_t)b * Hn + h) * Ln + lbase) * (size_t)Sn;
    const _Float16* __restrict__ ment = mh + ((size_t)h * Ln + lbase) * (size_t)Sn;

    for (int stc = 0; stc < 8; ++stc) {
        const int st = sh * 8 + stc;
        const int s0 = st * 64;
        const size_t tb = (((size_t)bh * 16 + st) * 8) * 512;

        // ---- V-fragment prefetch (overlaps the QK MFMA chain) ----
        h16x8 Vf[2][4];
#pragma unroll
        for (int kh = 0; kh < 2; ++kh) {
            const size_t kqb = tb + (size_t)(q + 4 * kh) * 512;
#pragma unroll
            for (int sub = 0; sub < 4; ++sub)
                Vf[kh][sub] = *(const h16x8*)(Vt + kqb + (size_t)(sub * 16 + n) * 8);
        }

        // ---- QK: acc1 = Q.K^T, acc2 = K.Q^T (f16 split, direct global B) ----
        f32x4 a1[4], a2[4];
#pragma unroll
        for (int i = 0; i < 4; ++i) {
            a1[i] = (f32x4){0.f, 0.f, 0.f, 0.f};
            a2[i] = (f32x4){0.f, 0.f, 0.f, 0.f};
        }
#pragma unroll
        for (int kh = 0; kh < 2; ++kh) {
            const size_t kqb = tb + (size_t)(q + 4 * kh) * 512;
#pragma unroll
            for (int sub = 0; sub < 4; ++sub) {
                const size_t off = kqb + (size_t)(sub * 16 + n) * 8;
                h16x8 KBh = *(const h16x8*)(Kh + off);
                h16x8 KBl = *(const h16x8*)(Kl + off);
                h16x8 QBh = *(const h16x8*)(Qh + off);
                h16x8 QBl = *(const h16x8*)(Ql + off);
                f32x4 x1 = a1[sub], x2 = a2[sub];
                x1 = __builtin_amdgcn_mfma_f32_16x16x32_f16(QAh[kh], KBh, x1, 0, 0, 0);
                x1 = __builtin_amdgcn_mfma_f32_16x16x32_f16(QAh[kh], KBl, x1, 0, 0, 0);
                x1 = __builtin_amdgcn_mfma_f32_16x16x32_f16(QAl[kh], KBh, x1, 0, 0, 0);
                x2 = __builtin_amdgcn_mfma_f32_16x16x32_f16(KAh[kh], QBh, x2, 0, 0, 0);
                x2 = __builtin_amdgcn_mfma_f32_16x16x32_f16(KAh[kh], QBl, x2, 0, 0, 0);
                x2 = __builtin_amdgcn_mfma_f32_16x16x32_f16(KAl[kh], QBh, x2, 0, 0, 0);
                a1[sub] = x1; a2[sub] = x2;
            }
        }

        // ---- elementwise chain, GROUPED (C-layout: row q*4+r, col sub*16+n) ----
#pragma unroll
        for (int sub = 0; sub < 4; ++sub) {
            const int s = s0 + sub * 16 + n;
#pragma unroll
            for (int r = 0; r < 4; ++r) {
                float mhv = (float)ment[(size_t)r * Sn + s];
                float cm = a1[sub][r] - a2[sub][r];
                // tanh(c1*cm) = 1 - 2/(exp2(c2l*cm)+1)
                float x = 1.0f - 2.0f * frcp(fexp2(c2l * cm) + 1.0f);
                // tanh-form gelu: x * sigmoid(1.5957691*(x + 0.044715 x^3))
                float t = x * fmaf(0.044715f * x, x, 1.0f);
                float g = x * frcp(1.0f + fexp2(-2.30221271f * t));
                float att = g * mhv;               // mh carries 0.125*m*hard
                __builtin_nontemporal_store(att, &arow[(size_t)r * Sn + s]);
                entp[r] += att * flog2(fmaxf(att, 1e-8f));
                plds[w][(q * 4 + r) * 72 + sub * 16 + n] = (_Float16)att;
            }
        }

        // ---- PV: accV += P . V (P A-frags from per-warp LDS, V in regs) ----
        {
            const _Float16* pw = &plds[w][0];
#pragma unroll
            for (int kh = 0; kh < 2; ++kh) {
                h16x8 Pf = *(const h16x8*)&pw[n * 72 + q * 8 + kh * 32];
#pragma unroll
                for (int sub = 0; sub < 4; ++sub) {
                    accV[sub] = __builtin_amdgcn_mfma_f32_16x16x32_f16(Pf, Vf[kh][sub], accV[sub], 0, 0, 0);
                }
            }
        }
    }

    // ---- epilogue: V partial sums via atomics (2 s-half blocks per l) ----
#pragma unroll
    for (int sub = 0; sub < 4; ++sub) {
#pragma unroll
        for (int r = 0; r < 4; ++r) {
            const int l = l0 + w * 16 + q * 4 + r;
            atomicAdd(Vout + (((size_t)b * Ln + l) * Hn + h) * En + sub * 16 + n, accV[sub][r]);
        }
    }
    // ---- entropy: quad-row reduce over 16 lanes, atomic partial (ln2 scale) ----
#pragma unroll
    for (int r = 0; r < 4; ++r) {
        float v = entp[r];
        v += __shfl_xor(v, 1);
        v += __shfl_xor(v, 2);
        v += __shfl_xor(v, 4);
        v += __shfl_xor(v, 8);
        if (n == 0) {
            atomicAdd(entOut + ((size_t)b * Hn + h) * Ln + lbase + r, -v * 0.69314718f);
        }
    }
}

extern "C" void kernel_launch(void* const* d_in, const int* in_sizes, int n_in,
                              void* d_out, int out_size, void* d_ws, size_t ws_size,
                              hipStream_t stream) {
    (void)in_sizes; (void)n_in; (void)ws_size; (void)out_size;

    const float* Q    = (const float*)d_in[0];   // (B,L,H,E)
    const float* K    = (const float*)d_in[1];   // (B,S,H,E)
    const float* Vv   = (const float*)d_in[2];   // (B,S,H,E)
    const float* phi  = (const float*)d_in[3];   // (H,L,S)
    const float* lg   = (const float*)d_in[4];
    const float* ltau = (const float*)d_in[5];
    const float* ltc  = (const float*)d_in[6];
    const float* hard = (const float*)d_in[7];   // (L,S)
    const float* u    = (const float*)d_in[8];   // (H,L,S)

    float* out  = (float*)d_out;
    float* Vout = out;                                 // B*L*H*E
    float* Aout = out + (size_t)Bn * Ln * Hn * En;     // B*H*L*S
    float* ent  = Aout + (size_t)Bn * Hn * Ln * Sn;    // B*H*L

    const size_t NE = (size_t)32 * 1024 * 64;          // 2.1M halves per array
    _Float16* Qh = (_Float16*)d_ws;
    _Float16* Ql = Qh + NE;
    _Float16* Kh = Ql + NE;
    _Float16* Kl = Kh + NE;
    _Float16* Vt = Kl + NE;
    _Float16* mh = Vt + NE;                            // H*L*S halves (16 MB)

    prep<<<dim3(64, 32), 256, 0, stream>>>(Q, K, Vv, Qh, Ql, Kh, Kl, Vt, Vout, ent);
    prep2<<<dim3(4096), 256, 0, stream>>>(phi, u, hard, ltau, mh);
    fused_lie<<<dim3(1024), 256, 0, stream>>>(Qh, Ql, Kh, Kl, Vt, mh,
                                              lg, ltc, Aout, Vout, ent);
}

// Round 9
// 317.043 us; speedup vs baseline: 1.2291x; 1.1772x over previous
//
#include <hip/hip_runtime.h>
#include <math.h>

#define Bn 4
#define Ln 1024
#define Sn 1024
#define Hn 8
#define En 64

typedef __attribute__((ext_vector_type(4))) float f32x4;
typedef __attribute__((ext_vector_type(8))) _Float16 h16x8;
typedef __attribute__((ext_vector_type(4))) _Float16 h16x4;

__device__ __forceinline__ float frcp(float x) { return __builtin_amdgcn_rcpf(x); }
__device__ __forceinline__ float fexp2(float x) {
    float r; asm("v_exp_f32 %0, %1" : "=v"(r) : "v"(x)); return r;
}
__device__ __forceinline__ float flog2(float x) {
    float r; asm("v_log_f32 %0, %1" : "=v"(r) : "v"(x)); return r;
}

// ---------------------------------------------------------------------------
// prep: split Q,K fp32 -> f16 hi/lo, fragment-major layout
//   [bh][tile][kq][row][8]; V -> f16 transposed tiles, same layout.
// 2048 blocks; folds Vout/ent zero-init (replaces 2 hipMemsetAsync nodes).
// ---------------------------------------------------------------------------
__global__ __launch_bounds__(256) void prep(
    const float* __restrict__ Q, const float* __restrict__ K,
    const float* __restrict__ V,
    _Float16* __restrict__ Qh, _Float16* __restrict__ Ql,
    _Float16* __restrict__ Kh, _Float16* __restrict__ Kl,
    _Float16* __restrict__ Vt, float* __restrict__ Vout,
    float* __restrict__ entOut) {
    __shared__ float vlds[16][69];
    const int bx = blockIdx.x;   // 0..63: st = bx>>2, row-group = bx&3
    const int st = bx >> 2;
    const int rg = bx & 3;
    const int bh = blockIdx.y;   // 0..31
    const int b = bh >> 3, h = bh & 7;
    const int tid = threadIdx.x;
    const int s0 = st * 64;

    // ---- zero-init Vout (4 f32/thread) and ent ----
    {
        const int flat = (blockIdx.y * 64 + bx) * 256 + tid;   // 0..524287
        *(f32x4*)(Vout + (size_t)flat * 4) = (f32x4){0.f, 0.f, 0.f, 0.f};
        if (flat < 8192) *(f32x4*)(entOut + (size_t)flat * 4) = (f32x4){0.f, 0.f, 0.f, 0.f};
    }

    // ---- load 16 rows, convert, store fragment-major; V slab to LDS ----
    {
        const int r16 = tid >> 4;            // 0..15
        const int c4 = (tid & 15) << 2;      // 0,4..60
        const int row = rg * 16 + r16;       // 0..63 in tile
        size_t gin = (((size_t)b * Ln + s0 + row) * Hn + h) * En + c4;
        f32x4 qv = *(const f32x4*)(Q + gin);
        f32x4 kv = *(const f32x4*)(K + gin);
        f32x4 vv = *(const f32x4*)(V + gin);
        vlds[r16][c4 + 0] = vv.x; vlds[r16][c4 + 1] = vv.y;
        vlds[r16][c4 + 2] = vv.z; vlds[r16][c4 + 3] = vv.w;
        h16x4 qh4, ql4, kh4, kl4;
#pragma unroll
        for (int j = 0; j < 4; ++j) {
            float x = qv[j];
            _Float16 hx = (_Float16)x;
            qh4[j] = hx; ql4[j] = (_Float16)(x - (float)hx);
            float y = kv[j];
            _Float16 hy = (_Float16)y;
            kh4[j] = hy; kl4[j] = (_Float16)(y - (float)hy);
        }
        size_t ob = ((((size_t)bh * 16 + st) * 8 + (c4 >> 3)) * 64 + row) * 8 + (c4 & 7);
        *(h16x4*)(Qh + ob) = qh4; *(h16x4*)(Ql + ob) = ql4;
        *(h16x4*)(Kh + ob) = kh4; *(h16x4*)(Kl + ob) = kl4;
    }
    __syncthreads();
    // ---- transposed V slab: 64 d-rows x 16 s-cols ----
    {
        const int d = tid >> 2;              // 0..63
        const int sgl = (tid & 3) << 2;      // 0,4,8,12
        h16x4 v4;
#pragma unroll
        for (int j = 0; j < 4; ++j) v4[j] = (_Float16)vlds[sgl + j][d];
        const int sg = rg * 16 + sgl;
        size_t ob = ((((size_t)bh * 16 + st) * 8 + (sg >> 3)) * 64 + d) * 8 + (sg & 7);
        *(h16x4*)(Vt + ob) = v4;
    }
}

// ---------------------------------------------------------------------------
// prep2: batch-independent mask precompute.
//   mh[h][l][s] = 0.125 * sigmoid((log(u+eps)-log(1-u+eps)+phi)/tau) * hard
// ---------------------------------------------------------------------------
__global__ __launch_bounds__(256) void prep2(
    const float* __restrict__ phi, const float* __restrict__ u,
    const float* __restrict__ hard, const float* __restrict__ p_lt,
    _Float16* __restrict__ mh) {
    const float tau = fminf(fmaxf(expf(p_lt[0]), 0.1f), 5.0f);
    const float itau = 1.0f / tau;
    const size_t base = ((size_t)blockIdx.x * 256 + threadIdx.x) * 8;
    const size_t ls = base & (size_t)(Ln * Sn - 1);
    f32x4 ph0 = *(const f32x4*)(phi + base);
    f32x4 ph1 = *(const f32x4*)(phi + base + 4);
    f32x4 uu0 = *(const f32x4*)(u + base);
    f32x4 uu1 = *(const f32x4*)(u + base + 4);
    f32x4 hm0 = *(const f32x4*)(hard + ls);
    f32x4 hm1 = *(const f32x4*)(hard + ls + 4);
    h16x8 o;
#pragma unroll
    for (int j = 0; j < 4; ++j) {
        float z = (__logf((uu0[j] + 1e-8f) * frcp(1.0f - uu0[j] + 1e-8f)) + ph0[j]) * itau;
        float m = frcp(1.0f + __expf(-z));
        o[j] = (_Float16)(0.125f * m * hm0[j]);
    }
#pragma unroll
    for (int j = 0; j < 4; ++j) {
        float z = (__logf((uu1[j] + 1e-8f) * frcp(1.0f - uu1[j] + 1e-8f)) + ph1[j]) * itau;
        float m = frcp(1.0f + __expf(-z));
        o[4 + j] = (_Float16)(0.125f * m * hm1[j]);
    }
    *(h16x8*)(mh + base) = o;
}

// ---------------------------------------------------------------------------
// fused: round-6 structure (proven 125us): barrier-free, XCD-pinned,
// grid 1024 (s-halves), NT A-stores with GROUPED EW + asm memory fences.
// FENCES ARE LOAD-HOISTING-HOSTILE BUT STORE-MERGING-ESSENTIAL: removing
// them (round 8) let the scheduler interleave loads between NT stores ->
// partial-line RMW -> FETCH 65->250 MB. Same failure per-sub (round 7).
// The EW/store grouping invariant: all stores covering one 128B line
// (2 subs x same r) must issue in one un-interleaved group.
// New: (a) QK split at 2-sub granularity (a1/a2 live range 32->16 regs;
// preserves the 128B-line invariant); (b) s_setprio(1) around MFMA
// clusters (barrier-free desynced waves = the regime where it pays).
// Occupancy is register-capped (VGPR64+acc64=128 -> 4 waves/SIMD): do not
// chase grid size (round 3: 2048 blocks, same 42%) and do not clamp
// launch_bounds below (256,4) (round 4: spilled 3x).
// ---------------------------------------------------------------------------
__global__ __launch_bounds__(256, 4) void fused_lie(
    const _Float16* __restrict__ Qh, const _Float16* __restrict__ Ql,
    const _Float16* __restrict__ Kh, const _Float16* __restrict__ Kl,
    const _Float16* __restrict__ Vt, const _Float16* __restrict__ mh,
    const float* __restrict__ p_lg, const float* __restrict__ p_ltc,
    float* __restrict__ Aout, float* __restrict__ Vout,
    float* __restrict__ entOut) {
    __shared__ __align__(16) _Float16 plds[4][16 * 72];

    // ---- XCD-pinned work decode (8 XCDs, flat%8 = XCD assumption) ----
    const int f = blockIdx.x;                 // 0..1023
    const int work = (f & 7) * 128 + (f >> 3);
    const int h = work >> 7;                  // 0..7  == XCD
    const int rem = work & 127;
    const int b = rem >> 5;                   // 0..3
    const int tile = rem & 31;
    const int lt = tile >> 1;                 // 0..15
    const int sh = tile & 1;                  // s-half 0..1
    const int bh = b * Hn + h;
    const int tid = threadIdx.x;
    const int w = tid >> 6;
    const int lane = tid & 63;
    const int q = lane >> 4;
    const int n = lane & 15;
    const int l0 = lt * 64;

    const float gain = fminf(fmaxf(expf(p_lg[0]), 1e-3f), 1000.0f);
    const float tauc = fminf(fmaxf(expf(p_ltc[0]), 1e-3f), 10.0f);
    const float c2l = 2.0f * gain / tauc * 1.44269504f;   // exp(c2*x) = exp2(c2l*x)

    // A-side fragments (registers): rows l0+w*16+n, k-chunk q+4*kh
    h16x8 QAh[2], QAl[2], KAh[2], KAl[2];
    {
        const size_t ab = (((size_t)bh * 16 + lt) * 8) * 512 + (size_t)(w * 16 + n) * 8;
#pragma unroll
        for (int kh = 0; kh < 2; ++kh) {
            size_t off = ab + (size_t)(q + 4 * kh) * 512;
            QAh[kh] = *(const h16x8*)(Qh + off);
            QAl[kh] = *(const h16x8*)(Ql + off);
            KAh[kh] = *(const h16x8*)(Kh + off);
            KAl[kh] = *(const h16x8*)(Kl + off);
        }
    }

    f32x4 accV[4];
#pragma unroll
    for (int i = 0; i < 4; ++i) accV[i] = (f32x4){0.f, 0.f, 0.f, 0.f};
    float entp[4] = {0.f, 0.f, 0.f, 0.f};

    const int lbase = l0 + w * 16 + q * 4;
    float* __restrict__ arow = Aout + (((size_t)b * Hn + h) * Ln + lbase) * (size_t)Sn;
    const _Float16* __restrict__ ment = mh + ((size_t)h * Ln + lbase) * (size_t)Sn;

    for (int stc = 0; stc < 8; ++stc) {
        const int st = sh * 8 + stc;
        const int s0 = st * 64;
        const size_t tb = (((size_t)bh * 16 + st) * 8) * 512;

        // ---- QK/EW in 2-sub groups (one 128B A-line per row per group) ----
#pragma unroll
        for (int sp = 0; sp < 2; ++sp) {
            f32x4 a1[2], a2[2];
#pragma unroll
            for (int i = 0; i < 2; ++i) {
                a1[i] = (f32x4){0.f, 0.f, 0.f, 0.f};
                a2[i] = (f32x4){0.f, 0.f, 0.f, 0.f};
            }
            __builtin_amdgcn_s_setprio(1);
#pragma unroll
            for (int kh = 0; kh < 2; ++kh) {
                const size_t kqb = tb + (size_t)(q + 4 * kh) * 512;
#pragma unroll
                for (int si = 0; si < 2; ++si) {
                    const int sub = sp * 2 + si;
                    const size_t off = kqb + (size_t)(sub * 16 + n) * 8;
                    h16x8 KBh = *(const h16x8*)(Kh + off);
                    h16x8 KBl = *(const h16x8*)(Kl + off);
                    h16x8 QBh = *(const h16x8*)(Qh + off);
                    h16x8 QBl = *(const h16x8*)(Ql + off);
                    f32x4 x1 = a1[si], x2 = a2[si];
                    x1 = __builtin_amdgcn_mfma_f32_16x16x32_f16(QAh[kh], KBh, x1, 0, 0, 0);
                    x1 = __builtin_amdgcn_mfma_f32_16x16x32_f16(QAh[kh], KBl, x1, 0, 0, 0);
                    x1 = __builtin_amdgcn_mfma_f32_16x16x32_f16(QAl[kh], KBh, x1, 0, 0, 0);
                    x2 = __builtin_amdgcn_mfma_f32_16x16x32_f16(KAh[kh], QBh, x2, 0, 0, 0);
                    x2 = __builtin_amdgcn_mfma_f32_16x16x32_f16(KAh[kh], QBl, x2, 0, 0, 0);
                    x2 = __builtin_amdgcn_mfma_f32_16x16x32_f16(KAl[kh], QBh, x2, 0, 0, 0);
                    a1[si] = x1; a2[si] = x2;
                }
            }
            __builtin_amdgcn_s_setprio(0);

            // ---- elementwise, grouped over the 2 subs (complete 128B lines) ----
#pragma unroll
            for (int si = 0; si < 2; ++si) {
                const int sub = sp * 2 + si;
                const int s = s0 + sub * 16 + n;
#pragma unroll
                for (int r = 0; r < 4; ++r) {
                    float mhv = (float)ment[(size_t)r * Sn + s];
                    float cm = a1[si][r] - a2[si][r];
                    // tanh(c1*cm) = 1 - 2/(exp2(c2l*cm)+1)
                    float x = 1.0f - 2.0f * frcp(fexp2(c2l * cm) + 1.0f);
                    // tanh-form gelu: x * sigmoid(1.5957691*(x + 0.044715 x^3))
                    float t = x * fmaf(0.044715f * x, x, 1.0f);
                    float g = x * frcp(1.0f + fexp2(-2.30221271f * t));
                    float att = g * mhv;               // mh carries 0.125*m*hard
                    __builtin_nontemporal_store(att, &arow[(size_t)r * Sn + s]);
                    entp[r] += att * flog2(fmaxf(att, 1e-8f));
                    plds[w][(q * 4 + r) * 72 + sub * 16 + n] = (_Float16)att;
                }
            }
        }
        asm volatile("" ::: "memory");   // pack NT stores; order plds w->r

        // ---- PV: accV += P . V (P A-frags from per-warp LDS, V^T global) ----
        {
            const _Float16* pw = &plds[w][0];
            __builtin_amdgcn_s_setprio(1);
#pragma unroll
            for (int kh = 0; kh < 2; ++kh) {
                const size_t kqb = tb + (size_t)(q + 4 * kh) * 512;
                h16x8 Pf = *(const h16x8*)&pw[n * 72 + q * 8 + kh * 32];
#pragma unroll
                for (int sub = 0; sub < 4; ++sub) {
                    h16x8 Vf = *(const h16x8*)(Vt + kqb + (size_t)(sub * 16 + n) * 8);
                    accV[sub] = __builtin_amdgcn_mfma_f32_16x16x32_f16(Pf, Vf, accV[sub], 0, 0, 0);
                }
            }
            __builtin_amdgcn_s_setprio(0);
        }
        asm volatile("" ::: "memory");   // order PV reads before next chunk's writes
    }

    // ---- epilogue: V partial sums via atomics (2 s-half blocks per l) ----
#pragma unroll
    for (int sub = 0; sub < 4; ++sub) {
#pragma unroll
        for (int r = 0; r < 4; ++r) {
            const int l = l0 + w * 16 + q * 4 + r;
            atomicAdd(Vout + (((size_t)b * Ln + l) * Hn + h) * En + sub * 16 + n, accV[sub][r]);
        }
    }
    // ---- entropy: quad-row reduce over 16 lanes, atomic partial (ln2 scale) ----
#pragma unroll
    for (int r = 0; r < 4; ++r) {
        float v = entp[r];
        v += __shfl_xor(v, 1);
        v += __shfl_xor(v, 2);
        v += __shfl_xor(v, 4);
        v += __shfl_xor(v, 8);
        if (n == 0) {
            atomicAdd(entOut + ((size_t)b * Hn + h) * Ln + lbase + r, -v * 0.69314718f);
        }
    }
}

extern "C" void kernel_launch(void* const* d_in, const int* in_sizes, int n_in,
                              void* d_out, int out_size, void* d_ws, size_t ws_size,
                              hipStream_t stream) {
    (void)in_sizes; (void)n_in; (void)ws_size; (void)out_size;

    const float* Q    = (const float*)d_in[0];   // (B,L,H,E)
    const float* K    = (const float*)d_in[1];   // (B,S,H,E)
    const float* Vv   = (const float*)d_in[2];   // (B,S,H,E)
    const float* phi  = (const float*)d_in[3];   // (H,L,S)
    const float* lg   = (const float*)d_in[4];
    const float* ltau = (const float*)d_in[5];
    const float* ltc  = (const float*)d_in[6];
    const float* hard = (const float*)d_in[7];   // (L,S)
    const float* u    = (const float*)d_in[8];   // (H,L,S)

    float* out  = (float*)d_out;
    float* Vout = out;                                 // B*L*H*E
    float* Aout = out + (size_t)Bn * Ln * Hn * En;     // B*H*L*S
    float* ent  = Aout + (size_t)Bn * Hn * Ln * Sn;    // B*H*L

    const size_t NE = (size_t)32 * 1024 * 64;          // 2.1M halves per array
    _Float16* Qh = (_Float16*)d_ws;
    _Float16* Ql = Qh + NE;
    _Float16* Kh = Ql + NE;
    _Float16* Kl = Kh + NE;
    _Float16* Vt = Kl + NE;
    _Float16* mh = Vt + NE;                            // H*L*S halves (16 MB)

    prep<<<dim3(64, 32), 256, 0, stream>>>(Q, K, Vv, Qh, Ql, Kh, Kl, Vt, Vout, ent);
    prep2<<<dim3(4096), 256, 0, stream>>>(phi, u, hard, ltau, mh);
    fused_lie<<<dim3(1024), 256, 0, stream>>>(Qh, Ql, Kh, Kl, Vt, mh,
                                              lg, ltc, Aout, Vout, ent);
}